// Round 7
// baseline (1352.149 us; speedup 1.0000x reference)
//
#include <hip/hip_runtime.h>
#include <hip/hip_bf16.h>
#include <cstdint>
#include <cstddef>

#define N_NODES 50000
#define N_EDGES 1600000
#define N_FEAT  512
#define N_HID   256
#define N_CLS   64
#define K_HOPS  10
#define NPAD    50016                       // plane rows incl. dummy zero row
#define DUMMY   N_NODES                     // pad edges point here (zeroed)
#define CH_STRIDE ((size_t)NPAD * 8)        // floats per 8-class chunk plane
#define P16(d) (((d) + 15) & ~15)
#define STAGE_CAP 256                       // csr entries staged in LDS per wave
#define HOP_GRID 25008                      // 8 chunks x 3126 blocks
#define NPS 6250                            // nodes per XCD slice (CSR build)

typedef __attribute__((ext_vector_type(4))) float f32x4;
typedef __attribute__((ext_vector_type(2))) float f32x2;
typedef __attribute__((ext_vector_type(8))) short s16x8;

__device__ __forceinline__ ushort f2bf(float f) {
    uint32_t u = __float_as_uint(f);
    uint32_t r = (u + 0x7FFFu + ((u >> 16) & 1u)) >> 16;
    return (ushort)r;
}

// packed fp32x2 -> bf16x2 (RNE), single VALU op — the staging converter
__device__ __forceinline__ uint32_t cvtpk(float a, float b) {
    uint32_t r;
    asm volatile("v_cvt_pk_bf16_f32 %0, %1, %2" : "=v"(r) : "v"(a), "v"(b));
    return r;
}

// ---------------- GEMM1: H = relu(X @ W1^T), bf16 MFMA, 128x128 tile, BK=64 ----
__launch_bounds__(256)
__global__ void gemm1_k(const float* __restrict__ X, const float* __restrict__ W1,
                        ushort* __restrict__ H) {
    __shared__ ushort sA[128 * 64];
    __shared__ ushort sB[128 * 64];
    const int m0 = blockIdx.x * 128;
    const int n0 = blockIdx.y * 128;
    const int t = threadIdx.x;
    const int wid = t >> 6, lane = t & 63;
    const int wr = wid >> 1, wc = wid & 1;
    const int lo = lane & 15, hi = lane >> 4;

    f32x4 acc[4][4] = {};

    for (int kt = 0; kt < N_FEAT; kt += 64) {
        #pragma unroll
        for (int p = 0; p < 8; ++p) {
            int idx = p * 256 + t;
            int row = idx >> 4, f4 = idx & 15;
            int grow = m0 + row; if (grow > N_NODES - 1) grow = N_NODES - 1;
            const float4 v = *reinterpret_cast<const float4*>(X + (size_t)grow * N_FEAT + kt + f4 * 4);
            uint2 h; h.x = cvtpk(v.x, v.y); h.y = cvtpk(v.z, v.w);
            int g = f4 >> 1;
            int off = row * 64 + (((g ^ (row & 7)) << 3)) + ((f4 & 1) << 2);
            *reinterpret_cast<uint2*>(&sA[off]) = h;
        }
        #pragma unroll
        for (int p = 0; p < 8; ++p) {
            int idx = p * 256 + t;
            int row = idx >> 4, f4 = idx & 15;
            const float4 v = *reinterpret_cast<const float4*>(W1 + (size_t)(n0 + row) * N_FEAT + kt + f4 * 4);
            uint2 h; h.x = cvtpk(v.x, v.y); h.y = cvtpk(v.z, v.w);
            int g = f4 >> 1;
            int off = row * 64 + (((g ^ (row & 7)) << 3)) + ((f4 & 1) << 2);
            *reinterpret_cast<uint2*>(&sB[off]) = h;
        }
        __syncthreads();
        #pragma unroll
        for (int kk = 0; kk < 2; ++kk) {
            const int g = kk * 4 + hi;
            s16x8 a[4], b[4];
            #pragma unroll
            for (int i = 0; i < 4; ++i) {
                int row = wr * 64 + i * 16 + lo;
                a[i] = *reinterpret_cast<const s16x8*>(&sA[row * 64 + ((g ^ (row & 7)) << 3)]);
            }
            #pragma unroll
            for (int j = 0; j < 4; ++j) {
                int row = wc * 64 + j * 16 + lo;
                b[j] = *reinterpret_cast<const s16x8*>(&sB[row * 64 + ((g ^ (row & 7)) << 3)]);
            }
            #pragma unroll
            for (int i = 0; i < 4; ++i)
                #pragma unroll
                for (int j = 0; j < 4; ++j)
                    acc[i][j] = __builtin_amdgcn_mfma_f32_16x16x32_bf16(a[i], b[j], acc[i][j], 0, 0, 0);
        }
        __syncthreads();
    }
    #pragma unroll
    for (int i = 0; i < 4; ++i) {
        int rbase = m0 + wr * 64 + i * 16 + hi * 4;
        #pragma unroll
        for (int j = 0; j < 4; ++j) {
            int col = n0 + wc * 64 + j * 16 + lo;
            #pragma unroll
            for (int r = 0; r < 4; ++r) {
                int row = rbase + r;
                if (row < N_NODES) {
                    float v = acc[i][j][r];
                    H[(size_t)row * N_HID + col] = f2bf(fmaxf(v, 0.0f));
                }
            }
        }
    }
}

// ---- GEMM2: h~0 = dinv * (H @ W2^T), chunk-major [8][NPAD][8] -----------------
__launch_bounds__(256)
__global__ void gemm2_k(const ushort* __restrict__ H, const float* __restrict__ W2,
                        const float* __restrict__ dinv, float* __restrict__ out) {
    __shared__ ushort sA[128 * 64];
    __shared__ ushort sB[64 * 64];
    const int m0 = blockIdx.x * 128;
    const int t = threadIdx.x;
    const int wid = t >> 6, lane = t & 63;
    const int lo = lane & 15, hi = lane >> 4;

    f32x4 acc[2][4] = {};

    for (int kt = 0; kt < N_HID; kt += 64) {
        #pragma unroll
        for (int p = 0; p < 4; ++p) {
            int idx = p * 256 + t;
            int row = idx >> 3, g = idx & 7;
            int grow = m0 + row; if (grow > N_NODES - 1) grow = N_NODES - 1;
            uint4 v = *reinterpret_cast<const uint4*>(H + (size_t)grow * N_HID + kt + g * 8);
            *reinterpret_cast<uint4*>(&sA[row * 64 + ((g ^ (row & 7)) << 3)]) = v;
        }
        #pragma unroll
        for (int p = 0; p < 4; ++p) {
            int idx = p * 256 + t;
            int row = idx >> 4, f4 = idx & 15;
            const float4 v = *reinterpret_cast<const float4*>(W2 + (size_t)row * N_HID + kt + f4 * 4);
            uint2 h; h.x = cvtpk(v.x, v.y); h.y = cvtpk(v.z, v.w);
            int g = f4 >> 1;
            int off = row * 64 + ((g ^ (row & 7)) << 3) + ((f4 & 1) << 2);
            *reinterpret_cast<uint2*>(&sB[off]) = h;
        }
        __syncthreads();
        #pragma unroll
        for (int kk = 0; kk < 2; ++kk) {
            const int g = kk * 4 + hi;
            s16x8 a[2], b[4];
            #pragma unroll
            for (int i = 0; i < 2; ++i) {
                int row = wid * 32 + i * 16 + lo;
                a[i] = *reinterpret_cast<const s16x8*>(&sA[row * 64 + ((g ^ (row & 7)) << 3)]);
            }
            #pragma unroll
            for (int j = 0; j < 4; ++j) {
                int row = j * 16 + lo;
                b[j] = *reinterpret_cast<const s16x8*>(&sB[row * 64 + ((g ^ (row & 7)) << 3)]);
            }
            #pragma unroll
            for (int i = 0; i < 2; ++i)
                #pragma unroll
                for (int j = 0; j < 4; ++j)
                    acc[i][j] = __builtin_amdgcn_mfma_f32_16x16x32_bf16(a[i], b[j], acc[i][j], 0, 0, 0);
        }
        __syncthreads();
    }
    // chunk-major store: class c = j*16+lo -> plane c>>3 = 2j+(lo>>3), within c&7
    #pragma unroll
    for (int i = 0; i < 2; ++i) {
        int rbase = m0 + wid * 32 + i * 16 + hi * 4;
        #pragma unroll
        for (int r = 0; r < 4; ++r) {
            int row = rbase + r;
            if (row < N_NODES) {
                const float dv = dinv[row];
                #pragma unroll
                for (int j = 0; j < 4; ++j) {
                    int plane = 2 * j + (lo >> 3);
                    out[(size_t)plane * CH_STRIDE + (size_t)row * 8 + (lo & 7)] = acc[i][j][r] * dv;
                }
            }
        }
    }
}

// ---------------- degree / dinv / rd (XCD-sliced deg) --------------------------
__global__ void deg_k(const int* __restrict__ dst, int* __restrict__ deg) {
    const int slice = blockIdx.x & 7;
    const int e = (blockIdx.x >> 3) * 256 + threadIdx.x;
    const int lo = slice * NPS;
    const int d = dst[e];
    if ((unsigned)(d - lo) < (unsigned)NPS) atomicAdd(&deg[d], 1);
}

__global__ void dinv_k(const int* __restrict__ deg, float* __restrict__ dinv,
                       float* __restrict__ rd) {
    int n = blockIdx.x * 256 + threadIdx.x;
    if (n < N_NODES) {
        float dp1 = (float)deg[n] + 1.0f;     // +1 self loop
        dinv[n] = rsqrtf(dp1);
        rd[n]   = sqrtf(dp1);
    }
}

// ------------- CSR build: scan over PADDED degrees + scatter + padfill ---------
__device__ __forceinline__ int wave_incl_scan(int v, int lane) {
    #pragma unroll
    for (int d = 1; d < 64; d <<= 1) {
        int u = __shfl_up(v, d, 64);
        if (lane >= d) v += u;
    }
    return v;
}

__global__ void scan_p1(const int* __restrict__ cnt, int* __restrict__ partial) {
    int i = blockIdx.x * 256 + threadIdx.x;
    int v = (i < N_NODES) ? P16(cnt[i]) : 0;
    #pragma unroll
    for (int d = 32; d; d >>= 1) v += __shfl_xor(v, d, 64);
    __shared__ int wt[4];
    int wid = threadIdx.x >> 6, lane = threadIdx.x & 63;
    if (lane == 0) wt[wid] = v;
    __syncthreads();
    if (threadIdx.x == 0) partial[blockIdx.x] = wt[0] + wt[1] + wt[2] + wt[3];
}

__global__ void scan_p2(const int* __restrict__ partial, int* __restrict__ chunkoff,
                        int* __restrict__ row_ptr) {
    int t = threadIdx.x;
    int v = (t < 196) ? partial[t] : 0;
    int lane = t & 63, wid = t >> 6;
    int incl = wave_incl_scan(v, lane);
    __shared__ int wt[4];
    if (lane == 63) wt[wid] = incl;
    __syncthreads();
    int woff = 0;
    for (int w = 0; w < wid; ++w) woff += wt[w];
    int excl = incl - v + woff;
    if (t < 196) chunkoff[t] = excl;
    if (t == 0) row_ptr[N_NODES] = wt[0] + wt[1] + wt[2] + wt[3];  // padded total
}

__global__ void scan_p3(const int* __restrict__ cnt, const int* __restrict__ chunkoff,
                        int* __restrict__ row_ptr) {
    int i = blockIdx.x * 256 + threadIdx.x;
    int v = (i < N_NODES) ? P16(cnt[i]) : 0;
    int lane = threadIdx.x & 63, wid = threadIdx.x >> 6;
    int incl = wave_incl_scan(v, lane);
    __shared__ int wt[4];
    if (lane == 63) wt[wid] = incl;
    __syncthreads();
    int woff = 0;
    for (int w = 0; w < wid; ++w) woff += wt[w];
    int excl = incl - v + woff;
    if (i < N_NODES) row_ptr[i] = chunkoff[blockIdx.x] + excl;
}

__global__ void scatter_k(const int* __restrict__ src, const int* __restrict__ dst,
                          const int* __restrict__ row_ptr,
                          int* __restrict__ cursor, int* __restrict__ csr) {
    const int slice = blockIdx.x & 7;
    const int e = (blockIdx.x >> 3) * 256 + threadIdx.x;
    const int lo = slice * NPS;
    const int d = dst[e];
    if ((unsigned)(d - lo) < (unsigned)NPS) {
        int pos = atomicAdd(&cursor[d], 1);
        csr[row_ptr[d] + pos] = src[e];
    }
}

__global__ void padfill_k(const int* __restrict__ deg, const int* __restrict__ row_ptr,
                          int* __restrict__ csr) {
    int n = blockIdx.x * 256 + threadIdx.x;
    if (n >= N_NODES) return;
    int d = deg[n];
    int base = row_ptr[n] + d;
    int pad = P16(d) - d;
    for (int i = 0; i < pad; ++i) csr[base + i] = DUMMY;
}

// zero the dummy row in all 8 chunk planes of the 3 state buffers
__global__ void zdum_k(float* __restrict__ b0, float* __restrict__ b1,
                       float* __restrict__ b2) {
    int t = threadIdx.x;
    if (t >= 192) return;
    float* b = (t < 64) ? b0 : (t < 128) ? b1 : b2;
    int w = t & 63;
    b[(size_t)(w >> 3) * CH_STRIDE + (size_t)DUMMY * 8 + (w & 7)] = 0.0f;
}

// ---------------- one APPNP hop: 8 chunks x 8 classes, chunk <-> XCD 1:1 -------
// p~'[d] = 0.9*dinv[d]^2*(sum_{s in N(d)} p~[s] + p~[d]) + 0.1*h~0[d]
// Planes chunk-major [8][NPAD][8] (32B rows). chunk = bid&7 -> ONE XCD owns a
// chunk end-to-end: per-XCD working set = prev 1.6MB + next 1.6MB = 3.2MB < 4MB
// L2, so NORMAL stores are safe (no r2-style thrash) and fill-on-miss makes the
// random gathers ~full L2-hits (~80 touches/line). csr + h0 stay nontemporal.
// Wave = 16 edge-slots x 4 lanes; lane loads f32x2 (4 lanes x 8B = 32B row).
__launch_bounds__(256)
__global__ void hop_k(const float* __restrict__ prev, const float* __restrict__ h0,
                      float* __restrict__ next, const int* __restrict__ csr,
                      const int* __restrict__ row_ptr, const float* __restrict__ dinv) {
    __shared__ int scsr[4][STAGE_CAP];
    const int bid = blockIdx.x;
    const int wid = threadIdx.x >> 6;
    const int lane = threadIdx.x & 63;
    const int chunk = bid & 7;                     // chunk == XCD slot
    const int cb = bid >> 3;                       // within-chunk block id
    const int nb = cb * 16 + wid * 4;              // first of this wave's 4 nodes
    if (nb >= N_NODES) return;
    const int slot = lane >> 2;                    // edge slot 0..15
    const int cl2 = (lane & 3) << 1;               // float offset in 8-f row

    const float* __restrict__ pc = prev + (size_t)chunk * CH_STRIDE;
    const float* __restrict__ hc = h0   + (size_t)chunk * CH_STRIDE;
    float*       __restrict__ nc = next + (size_t)chunk * CH_STRIDE;

    // padded segment boundaries -> SGPRs (uniform loop bounds)
    const int b0 = __builtin_amdgcn_readfirstlane(row_ptr[nb]);
    const int e0 = __builtin_amdgcn_readfirstlane(row_ptr[nb + 1]);
    const int e1 = __builtin_amdgcn_readfirstlane(row_ptr[nb + 2]);
    const int e2 = __builtin_amdgcn_readfirstlane(row_ptr[nb + 3]);
    const int e3 = __builtin_amdgcn_readfirstlane(row_ptr[nb + 4]);
    const int tot = e3 - b0;

    // stage combined range into LDS (4 independent nt loads per lane)
    int* sw = scsr[wid];
    #pragma unroll
    for (int k = 0; k < 4; ++k) {
        int off = k * 64 + lane;
        if (off < tot && off < STAGE_CAP)
            sw[off] = __builtin_nontemporal_load(csr + b0 + off);
    }

    f32x2 a0 = {0.f, 0.f}, a1 = a0, a2 = a0, a3 = a0;

#define NODE_LOOP(Bg, Eg, ACC)                                                   \
    for (int ib = (Bg); ib < (Eg); ib += 16) {                                   \
        int s;                                                                   \
        if (ib - b0 < STAGE_CAP) s = sw[ib - b0 + slot];                         \
        else s = __builtin_nontemporal_load(csr + ib + slot);                    \
        const f32x2 p = *reinterpret_cast<const f32x2*>(                         \
            pc + (size_t)s * 8 + cl2);                                           \
        ACC[0] += p[0]; ACC[1] += p[1];                                          \
    }

    NODE_LOOP(b0, e0, a0)
    NODE_LOOP(e0, e1, a1)
    NODE_LOOP(e1, e2, a2)
    NODE_LOOP(e2, e3, a3)
#undef NODE_LOOP

    // fold 16 slots (lane bits 2..5) for each node's accumulator
    #pragma unroll
    for (int d = 4; d <= 32; d <<= 1) {
        a0[0] += __shfl_xor(a0[0], d, 64); a0[1] += __shfl_xor(a0[1], d, 64);
        a1[0] += __shfl_xor(a1[0], d, 64); a1[1] += __shfl_xor(a1[1], d, 64);
        a2[0] += __shfl_xor(a2[0], d, 64); a2[1] += __shfl_xor(a2[1], d, 64);
        a3[0] += __shfl_xor(a3[0], d, 64); a3[1] += __shfl_xor(a3[1], d, 64);
    }

    // slots 0..3 each own one node: 4 lanes x 8B = contiguous 32B row store
    if (slot < 4) {
        const int node = nb + slot;
        const float di = dinv[node];
        const float di2 = di * di;
        f32x2 av = a0;
        if (slot == 1) av = a1;
        if (slot == 2) av = a2;
        if (slot == 3) av = a3;
        const size_t off = (size_t)node * 8 + cl2;
        const f32x2 pv = *reinterpret_cast<const f32x2*>(pc + off);  // L2-hit
        const f32x2 hh = __builtin_nontemporal_load(
            reinterpret_cast<const f32x2*>(hc + off));
        f32x2 r;
        r[0] = 0.9f * di2 * (av[0] + pv[0]) + 0.1f * hh[0];
        r[1] = 0.9f * di2 * (av[1] + pv[1]) + 0.1f * hh[1];
        *reinterpret_cast<f32x2*>(nc + off) = r;   // NORMAL store: stay in L2
    }
}

// ---- log_softmax over 64 classes; input scaled planes, rescale by rd ----------
__launch_bounds__(256)
__global__ void logsm_k(const float* __restrict__ in, const float* __restrict__ rd,
                        float* __restrict__ out) {
    int r = (blockIdx.x * 256 + threadIdx.x) >> 6;
    int lane = threadIdx.x & 63;
    if (r >= N_NODES) return;
    float v = in[(size_t)(lane >> 3) * CH_STRIDE + (size_t)r * 8 + (lane & 7)] * rd[r];
    float m = v;
    #pragma unroll
    for (int d = 32; d; d >>= 1) m = fmaxf(m, __shfl_xor(m, d, 64));
    float e = __expf(v - m);
    float s = e;
    #pragma unroll
    for (int d = 32; d; d >>= 1) s += __shfl_xor(s, d, 64);
    out[(size_t)r * N_CLS + lane] = (v - m) - __logf(s);
}

extern "C" void kernel_launch(void* const* d_in, const int* in_sizes, int n_in,
                              void* d_out, int out_size, void* d_ws, size_t ws_size,
                              hipStream_t stream) {
    const float* X  = (const float*)d_in[0];
    const int*   EI = (const int*)d_in[1];
    const float* W1 = (const float*)d_in[2];
    const float* W2 = (const float*)d_in[3];
    const int* src = EI;
    const int* dst = EI + N_EDGES;

    char* ws = (char*)d_ws;
    const size_t BUF = 8 * CH_STRIDE * sizeof(float);   // 12,804,096 B
    ushort* H      = (ushort*)(ws + 0);                 // 25,600,000 B
    float*  h0t    = (float*)(ws + 25600000);           // BUF (h~0, chunk-major)
    float*  pp0    = (float*)(ws + 25600000 + BUF);     // BUF
    float*  pp1    = (float*)(ws + 25600000 + 2*BUF);   // BUF
    int*    csr    = (int*)  (ws + 64012288);           // <= 9,600,000 B (padded, 4B)
    int*    deg    = (int*)  (ws + 73612288);           // 200,000 B
    float*  dinv   = (float*)(ws + 73812288);           // 200,000 B
    float*  rd     = (float*)(ws + 74012288);           // 200,000 B
    int*    rptr   = (int*)  (ws + 74212288);           // 200,004 B
    int*    cursor = (int*)  (ws + 74412292);           // 200,000 B
    int*    part   = (int*)  (ws + 74612292);           // 784 B
    int*    coff   = (int*)  (ws + 74613076);           // 784 B

    hipMemsetAsync(deg, 0, N_NODES * sizeof(int), stream);
    hipMemsetAsync(cursor, 0, N_NODES * sizeof(int), stream);

    deg_k<<<50000, 256, 0, stream>>>(dst, deg);
    dinv_k<<<196, 256, 0, stream>>>(deg, dinv, rd);
    scan_p1<<<196, 256, 0, stream>>>(deg, part);
    scan_p2<<<1, 256, 0, stream>>>(part, coff, rptr);
    scan_p3<<<196, 256, 0, stream>>>(deg, coff, rptr);
    scatter_k<<<50000, 256, 0, stream>>>(src, dst, rptr, cursor, csr);
    padfill_k<<<196, 256, 0, stream>>>(deg, rptr, csr);
    zdum_k<<<1, 256, 0, stream>>>(h0t, pp0, pp1);

    gemm1_k<<<dim3(391, 2), 256, 0, stream>>>(X, W1, H);
    gemm2_k<<<391, 256, 0, stream>>>(H, W2, dinv, h0t);

    const float* p = h0t;
    float* bufs[2] = {pp0, pp1};
    for (int k = 0; k < K_HOPS; ++k) {
        float* nx = bufs[k & 1];
        hop_k<<<HOP_GRID, 256, 0, stream>>>(p, h0t, nx, csr, rptr, dinv);
        p = nx;
    }
    logsm_k<<<12500, 256, 0, stream>>>(p, rd, (float*)d_out);
}

// Round 8
// 897.531 us; speedup vs baseline: 1.5065x; 1.5065x over previous
//
#include <hip/hip_runtime.h>
#include <hip/hip_bf16.h>
#include <cstdint>
#include <cstddef>

#define N_NODES 50000
#define N_EDGES 1600000
#define N_FEAT  512
#define N_HID   256
#define N_CLS   64
#define K_HOPS  10
#define NPAD    50016                       // plane rows incl. dummy zero row
#define DUMMY   N_NODES                     // pad edges point here (zeroed)
#define CH_STRIDE ((size_t)NPAD * 16)       // floats per 16-class chunk plane
#define P16(d) (((d) + 15) & ~15)
#define STAGE_CAP 256                       // csr entries staged in LDS per wave
#define HOP_GRID 12504                      // 4 chunks x 3126 blocks, 8 | grid
#define NPS 6250                            // nodes per XCD slice (CSR build)

typedef __attribute__((ext_vector_type(4))) float f32x4;
typedef __attribute__((ext_vector_type(8))) short s16x8;

__device__ __forceinline__ ushort f2bf(float f) {
    uint32_t u = __float_as_uint(f);
    uint32_t r = (u + 0x7FFFu + ((u >> 16) & 1u)) >> 16;
    return (ushort)r;
}

// packed fp32x2 -> bf16x2, single VALU op. NON-volatile: pure, schedulable.
__device__ __forceinline__ uint32_t cvtpk(float a, float b) {
    uint32_t r;
    asm("v_cvt_pk_bf16_f32 %0, %1, %2" : "=v"(r) : "v"(a), "v"(b));
    return r;
}

// ------- prepass: X (and W1) fp32 -> bf16, pure streaming, full occupancy ------
__global__ void xb_k(const float* __restrict__ X, const float* __restrict__ W1,
                     ushort* __restrict__ Xb, ushort* __restrict__ W1b) {
    const size_t NX = (size_t)N_NODES * N_FEAT;   // 25,600,000
    const size_t NW = (size_t)N_HID * N_FEAT;     // 131,072
    size_t i = ((size_t)blockIdx.x * 256 + threadIdx.x) * 8;
    if (i < NX) {
        const f32x4 a = *reinterpret_cast<const f32x4*>(X + i);
        const f32x4 b = *reinterpret_cast<const f32x4*>(X + i + 4);
        uint4 o;
        o.x = cvtpk(a[0], a[1]); o.y = cvtpk(a[2], a[3]);
        o.z = cvtpk(b[0], b[1]); o.w = cvtpk(b[2], b[3]);
        *reinterpret_cast<uint4*>(Xb + i) = o;
    } else {
        size_t j = i - NX;
        if (j < NW) {
            const f32x4 a = *reinterpret_cast<const f32x4*>(W1 + j);
            const f32x4 b = *reinterpret_cast<const f32x4*>(W1 + j + 4);
            uint4 o;
            o.x = cvtpk(a[0], a[1]); o.y = cvtpk(a[2], a[3]);
            o.z = cvtpk(b[0], b[1]); o.w = cvtpk(b[2], b[3]);
            *reinterpret_cast<uint4*>(W1b + j) = o;
        }
    }
}

// ---- GEMM1: H = relu(Xb @ W1b^T), bf16 inputs, pure-copy staging --------------
__launch_bounds__(256)
__global__ void gemm1_k(const ushort* __restrict__ Xb, const ushort* __restrict__ W1b,
                        ushort* __restrict__ H) {
    __shared__ ushort sA[128 * 64];
    __shared__ ushort sB[128 * 64];
    const int m0 = blockIdx.x * 128;
    const int n0 = blockIdx.y * 128;
    const int t = threadIdx.x;
    const int wid = t >> 6, lane = t & 63;
    const int wr = wid >> 1, wc = wid & 1;
    const int lo = lane & 15, hi = lane >> 4;

    f32x4 acc[4][4] = {};

    for (int kt = 0; kt < N_FEAT; kt += 64) {
        // stage A: Xb tile 128x64 bf16, direct 16B copies
        #pragma unroll
        for (int p = 0; p < 4; ++p) {
            int idx = p * 256 + t;
            int row = idx >> 3, g = idx & 7;
            int grow = m0 + row; if (grow > N_NODES - 1) grow = N_NODES - 1;
            uint4 v = *reinterpret_cast<const uint4*>(Xb + (size_t)grow * N_FEAT + kt + g * 8);
            *reinterpret_cast<uint4*>(&sA[row * 64 + ((g ^ (row & 7)) << 3)]) = v;
        }
        // stage B: W1b rows n0..n0+127, direct 16B copies
        #pragma unroll
        for (int p = 0; p < 4; ++p) {
            int idx = p * 256 + t;
            int row = idx >> 3, g = idx & 7;
            uint4 v = *reinterpret_cast<const uint4*>(W1b + (size_t)(n0 + row) * N_FEAT + kt + g * 8);
            *reinterpret_cast<uint4*>(&sB[row * 64 + ((g ^ (row & 7)) << 3)]) = v;
        }
        __syncthreads();
        #pragma unroll
        for (int kk = 0; kk < 2; ++kk) {
            const int g = kk * 4 + hi;
            s16x8 a[4], b[4];
            #pragma unroll
            for (int i = 0; i < 4; ++i) {
                int row = wr * 64 + i * 16 + lo;
                a[i] = *reinterpret_cast<const s16x8*>(&sA[row * 64 + ((g ^ (row & 7)) << 3)]);
            }
            #pragma unroll
            for (int j = 0; j < 4; ++j) {
                int row = wc * 64 + j * 16 + lo;
                b[j] = *reinterpret_cast<const s16x8*>(&sB[row * 64 + ((g ^ (row & 7)) << 3)]);
            }
            #pragma unroll
            for (int i = 0; i < 4; ++i)
                #pragma unroll
                for (int j = 0; j < 4; ++j)
                    acc[i][j] = __builtin_amdgcn_mfma_f32_16x16x32_bf16(a[i], b[j], acc[i][j], 0, 0, 0);
        }
        __syncthreads();
    }
    #pragma unroll
    for (int i = 0; i < 4; ++i) {
        int rbase = m0 + wr * 64 + i * 16 + hi * 4;
        #pragma unroll
        for (int j = 0; j < 4; ++j) {
            int col = n0 + wc * 64 + j * 16 + lo;
            #pragma unroll
            for (int r = 0; r < 4; ++r) {
                int row = rbase + r;
                if (row < N_NODES) {
                    float v = acc[i][j][r];
                    H[(size_t)row * N_HID + col] = f2bf(fmaxf(v, 0.0f));
                }
            }
        }
    }
}

// ---- GEMM2: h~0 = dinv * (H @ W2^T), chunk-major [4][NPAD][16] ----------------
__launch_bounds__(256)
__global__ void gemm2_k(const ushort* __restrict__ H, const float* __restrict__ W2,
                        const float* __restrict__ dinv, float* __restrict__ out) {
    __shared__ ushort sA[128 * 64];
    __shared__ ushort sB[64 * 64];
    const int m0 = blockIdx.x * 128;
    const int t = threadIdx.x;
    const int wid = t >> 6, lane = t & 63;
    const int lo = lane & 15, hi = lane >> 4;

    f32x4 acc[2][4] = {};

    for (int kt = 0; kt < N_HID; kt += 64) {
        #pragma unroll
        for (int p = 0; p < 4; ++p) {
            int idx = p * 256 + t;
            int row = idx >> 3, g = idx & 7;
            int grow = m0 + row; if (grow > N_NODES - 1) grow = N_NODES - 1;
            uint4 v = *reinterpret_cast<const uint4*>(H + (size_t)grow * N_HID + kt + g * 8);
            *reinterpret_cast<uint4*>(&sA[row * 64 + ((g ^ (row & 7)) << 3)]) = v;
        }
        #pragma unroll
        for (int p = 0; p < 4; ++p) {
            int idx = p * 256 + t;
            int row = idx >> 4, f4 = idx & 15;
            const float4 v = *reinterpret_cast<const float4*>(W2 + (size_t)row * N_HID + kt + f4 * 4);
            uint2 h; h.x = cvtpk(v.x, v.y); h.y = cvtpk(v.z, v.w);
            int g = f4 >> 1;
            int off = row * 64 + ((g ^ (row & 7)) << 3) + ((f4 & 1) << 2);
            *reinterpret_cast<uint2*>(&sB[off]) = h;
        }
        __syncthreads();
        #pragma unroll
        for (int kk = 0; kk < 2; ++kk) {
            const int g = kk * 4 + hi;
            s16x8 a[2], b[4];
            #pragma unroll
            for (int i = 0; i < 2; ++i) {
                int row = wid * 32 + i * 16 + lo;
                a[i] = *reinterpret_cast<const s16x8*>(&sA[row * 64 + ((g ^ (row & 7)) << 3)]);
            }
            #pragma unroll
            for (int j = 0; j < 4; ++j) {
                int row = j * 16 + lo;
                b[j] = *reinterpret_cast<const s16x8*>(&sB[row * 64 + ((g ^ (row & 7)) << 3)]);
            }
            #pragma unroll
            for (int i = 0; i < 2; ++i)
                #pragma unroll
                for (int j = 0; j < 4; ++j)
                    acc[i][j] = __builtin_amdgcn_mfma_f32_16x16x32_bf16(a[i], b[j], acc[i][j], 0, 0, 0);
        }
        __syncthreads();
    }
    // chunk-major store: class col = j*16+lo -> plane j, within lo; scaled by dinv
    #pragma unroll
    for (int i = 0; i < 2; ++i) {
        int rbase = m0 + wid * 32 + i * 16 + hi * 4;
        #pragma unroll
        for (int r = 0; r < 4; ++r) {
            int row = rbase + r;
            if (row < N_NODES) {
                const float dv = dinv[row];
                #pragma unroll
                for (int j = 0; j < 4; ++j)
                    out[(size_t)j * CH_STRIDE + (size_t)row * 16 + lo] = acc[i][j][r] * dv;
            }
        }
    }
}

// ---------------- degree / dinv / rd (XCD-sliced deg) --------------------------
__global__ void deg_k(const int* __restrict__ dst, int* __restrict__ deg) {
    const int slice = blockIdx.x & 7;
    const int e = (blockIdx.x >> 3) * 256 + threadIdx.x;
    const int lo = slice * NPS;
    const int d = dst[e];
    if ((unsigned)(d - lo) < (unsigned)NPS) atomicAdd(&deg[d], 1);
}

__global__ void dinv_k(const int* __restrict__ deg, float* __restrict__ dinv,
                       float* __restrict__ rd) {
    int n = blockIdx.x * 256 + threadIdx.x;
    if (n < N_NODES) {
        float dp1 = (float)deg[n] + 1.0f;     // +1 self loop
        dinv[n] = rsqrtf(dp1);
        rd[n]   = sqrtf(dp1);
    }
}

// ------------- CSR build: scan over PADDED degrees + scatter + padfill ---------
__device__ __forceinline__ int wave_incl_scan(int v, int lane) {
    #pragma unroll
    for (int d = 1; d < 64; d <<= 1) {
        int u = __shfl_up(v, d, 64);
        if (lane >= d) v += u;
    }
    return v;
}

__global__ void scan_p1(const int* __restrict__ cnt, int* __restrict__ partial) {
    int i = blockIdx.x * 256 + threadIdx.x;
    int v = (i < N_NODES) ? P16(cnt[i]) : 0;
    #pragma unroll
    for (int d = 32; d; d >>= 1) v += __shfl_xor(v, d, 64);
    __shared__ int wt[4];
    int wid = threadIdx.x >> 6, lane = threadIdx.x & 63;
    if (lane == 0) wt[wid] = v;
    __syncthreads();
    if (threadIdx.x == 0) partial[blockIdx.x] = wt[0] + wt[1] + wt[2] + wt[3];
}

__global__ void scan_p2(const int* __restrict__ partial, int* __restrict__ chunkoff,
                        int* __restrict__ row_ptr) {
    int t = threadIdx.x;
    int v = (t < 196) ? partial[t] : 0;
    int lane = t & 63, wid = t >> 6;
    int incl = wave_incl_scan(v, lane);
    __shared__ int wt[4];
    if (lane == 63) wt[wid] = incl;
    __syncthreads();
    int woff = 0;
    for (int w = 0; w < wid; ++w) woff += wt[w];
    int excl = incl - v + woff;
    if (t < 196) chunkoff[t] = excl;
    if (t == 0) row_ptr[N_NODES] = wt[0] + wt[1] + wt[2] + wt[3];  // padded total
}

__global__ void scan_p3(const int* __restrict__ cnt, const int* __restrict__ chunkoff,
                        int* __restrict__ row_ptr) {
    int i = blockIdx.x * 256 + threadIdx.x;
    int v = (i < N_NODES) ? P16(cnt[i]) : 0;
    int lane = threadIdx.x & 63, wid = threadIdx.x >> 6;
    int incl = wave_incl_scan(v, lane);
    __shared__ int wt[4];
    if (lane == 63) wt[wid] = incl;
    __syncthreads();
    int woff = 0;
    for (int w = 0; w < wid; ++w) woff += wt[w];
    int excl = incl - v + woff;
    if (i < N_NODES) row_ptr[i] = chunkoff[blockIdx.x] + excl;
}

__global__ void scatter_k(const int* __restrict__ src, const int* __restrict__ dst,
                          const int* __restrict__ row_ptr,
                          int* __restrict__ cursor, int* __restrict__ csr) {
    const int slice = blockIdx.x & 7;
    const int e = (blockIdx.x >> 3) * 256 + threadIdx.x;
    const int lo = slice * NPS;
    const int d = dst[e];
    if ((unsigned)(d - lo) < (unsigned)NPS) {
        int pos = atomicAdd(&cursor[d], 1);
        csr[row_ptr[d] + pos] = src[e];
    }
}

__global__ void padfill_k(const int* __restrict__ deg, const int* __restrict__ row_ptr,
                          int* __restrict__ csr) {
    int n = blockIdx.x * 256 + threadIdx.x;
    if (n >= N_NODES) return;
    int d = deg[n];
    int base = row_ptr[n] + d;
    int pad = P16(d) - d;
    for (int i = 0; i < pad; ++i) csr[base + i] = DUMMY;
}

// zero the dummy row in all 4 chunk planes of the 3 state buffers
__global__ void zdum_k(float* __restrict__ b0, float* __restrict__ b1,
                       float* __restrict__ b2) {
    int t = threadIdx.x;
    if (t >= 192) return;
    float* b = (t < 64) ? b0 : (t < 128) ? b1 : b2;
    int w = t & 63;
    b[(size_t)(w >> 4) * CH_STRIDE + (size_t)DUMMY * 16 + (w & 15)] = 0.0f;
}

// ---------------- one APPNP hop: weightless scaled planes (r5-proven) ----------
// p~'[d] = 0.9*dinv[d]^2*(sum_{s in N(d)} p~[s] + p~[d]) + 0.1*h~0[d]
// Planes chunk-major [4][NPAD][16], chunk pinned to XCD pair. csr = 4B src
// indices, padded to 16-multiples with DUMMY (zero row). Wave = 16 slots x 4
// lanes, 4 nodes/wave, combined segment LDS-staged with 4 parallel nt loads.
__launch_bounds__(256)
__global__ void hop_k(const float* __restrict__ prev, const float* __restrict__ h0,
                      float* __restrict__ next, const int* __restrict__ csr,
                      const int* __restrict__ row_ptr, const float* __restrict__ dinv) {
    __shared__ int scsr[4][STAGE_CAP];
    const int bid = blockIdx.x;
    const int wid = threadIdx.x >> 6;
    const int lane = threadIdx.x & 63;
    const int xs = bid & 7;
    const int chunk = xs >> 1;
    const int cb = ((bid >> 3) << 1) | (xs & 1);   // within-chunk block id
    const int nb = cb * 16 + wid * 4;              // first of this wave's 4 nodes
    if (nb >= N_NODES) return;
    const int slot = lane >> 2;                    // edge slot 0..15
    const int cl4 = (lane & 3) << 2;               // float offset in 16-f row

    const float* __restrict__ pc = prev + (size_t)chunk * CH_STRIDE;
    const float* __restrict__ hc = h0   + (size_t)chunk * CH_STRIDE;
    float*       __restrict__ nc = next + (size_t)chunk * CH_STRIDE;

    const int b0 = __builtin_amdgcn_readfirstlane(row_ptr[nb]);
    const int e0 = __builtin_amdgcn_readfirstlane(row_ptr[nb + 1]);
    const int e1 = __builtin_amdgcn_readfirstlane(row_ptr[nb + 2]);
    const int e2 = __builtin_amdgcn_readfirstlane(row_ptr[nb + 3]);
    const int e3 = __builtin_amdgcn_readfirstlane(row_ptr[nb + 4]);
    const int tot = e3 - b0;

    int* sw = scsr[wid];
    #pragma unroll
    for (int k = 0; k < 4; ++k) {
        int off = k * 64 + lane;
        if (off < tot && off < STAGE_CAP)
            sw[off] = __builtin_nontemporal_load(csr + b0 + off);
    }

    f32x4 a0 = {0.f,0.f,0.f,0.f}, a1 = a0, a2 = a0, a3 = a0;

#define NODE_LOOP(Bg, Eg, ACC)                                                   \
    for (int ib = (Bg); ib < (Eg); ib += 16) {                                   \
        int s;                                                                   \
        if (ib - b0 < STAGE_CAP) s = sw[ib - b0 + slot];                         \
        else s = __builtin_nontemporal_load(csr + ib + slot);                    \
        const f32x4 p = *reinterpret_cast<const f32x4*>(                         \
            pc + (size_t)s * 16 + cl4);                                          \
        ACC[0] += p[0]; ACC[1] += p[1]; ACC[2] += p[2]; ACC[3] += p[3];          \
    }

    NODE_LOOP(b0, e0, a0)
    NODE_LOOP(e0, e1, a1)
    NODE_LOOP(e1, e2, a2)
    NODE_LOOP(e2, e3, a3)
#undef NODE_LOOP

    #pragma unroll
    for (int c = 0; c < 4; ++c) {
        a0[c] += __shfl_xor(a0[c], 4, 64);  a0[c] += __shfl_xor(a0[c], 8, 64);
        a0[c] += __shfl_xor(a0[c], 16, 64); a0[c] += __shfl_xor(a0[c], 32, 64);
        a1[c] += __shfl_xor(a1[c], 4, 64);  a1[c] += __shfl_xor(a1[c], 8, 64);
        a1[c] += __shfl_xor(a1[c], 16, 64); a1[c] += __shfl_xor(a1[c], 32, 64);
        a2[c] += __shfl_xor(a2[c], 4, 64);  a2[c] += __shfl_xor(a2[c], 8, 64);
        a2[c] += __shfl_xor(a2[c], 16, 64); a2[c] += __shfl_xor(a2[c], 32, 64);
        a3[c] += __shfl_xor(a3[c], 4, 64);  a3[c] += __shfl_xor(a3[c], 8, 64);
        a3[c] += __shfl_xor(a3[c], 16, 64); a3[c] += __shfl_xor(a3[c], 32, 64);
    }

    if (slot < 4) {
        const int node = nb + slot;
        const float di = dinv[node];
        const float di2 = di * di;
        f32x4 av = a0;
        if (slot == 1) av = a1;
        if (slot == 2) av = a2;
        if (slot == 3) av = a3;
        const size_t off = (size_t)node * 16 + cl4;
        const f32x4 pv = *reinterpret_cast<const f32x4*>(pc + off);   // L2-resident
        const f32x4 hh = __builtin_nontemporal_load(
            reinterpret_cast<const f32x4*>(hc + off));
        f32x4 r;
        #pragma unroll
        for (int c = 0; c < 4; ++c)
            r[c] = 0.9f * di2 * (av[c] + pv[c]) + 0.1f * hh[c];
        __builtin_nontemporal_store(r, reinterpret_cast<f32x4*>(nc + off));
    }
}

// ---- log_softmax over 64 classes; input scaled planes, rescale by rd ----------
__launch_bounds__(256)
__global__ void logsm_k(const float* __restrict__ in, const float* __restrict__ rd,
                        float* __restrict__ out) {
    int r = (blockIdx.x * 256 + threadIdx.x) >> 6;
    int lane = threadIdx.x & 63;
    if (r >= N_NODES) return;
    float v = in[(size_t)(lane >> 4) * CH_STRIDE + (size_t)r * 16 + (lane & 15)] * rd[r];
    float m = v;
    #pragma unroll
    for (int d = 32; d; d >>= 1) m = fmaxf(m, __shfl_xor(m, d, 64));
    float e = __expf(v - m);
    float s = e;
    #pragma unroll
    for (int d = 32; d; d >>= 1) s += __shfl_xor(s, d, 64);
    out[(size_t)r * N_CLS + lane] = (v - m) - __logf(s);
}

extern "C" void kernel_launch(void* const* d_in, const int* in_sizes, int n_in,
                              void* d_out, int out_size, void* d_ws, size_t ws_size,
                              hipStream_t stream) {
    const float* X  = (const float*)d_in[0];
    const int*   EI = (const int*)d_in[1];
    const float* W1 = (const float*)d_in[2];
    const float* W2 = (const float*)d_in[3];
    const int* src = EI;
    const int* dst = EI + N_EDGES;

    char* ws = (char*)d_ws;
    // Lifetimes: Xb/W1b live [xb_k, gemm1]; the hop-state region reuses the
    // same bytes afterwards (stream-ordered). H lives [gemm1, gemm2].
    // Peak: Xb+W1b+H = 77.06 MB (same footprint as prior rounds).
    ushort* Xb     = (ushort*)(ws + 0);                 // 51,200,000 B
    ushort* W1b    = (ushort*)(ws + 51200000);          //    262,144 B
    ushort* H      = (ushort*)(ws + 51462144);          // 25,600,000 B
    // reuse of [0, 51.2MB) after gemm1:
    float*  h0t    = (float*)(ws + 0);                  // 12,804,096 B
    float*  pp0    = (float*)(ws + 12804096);           // 12,804,096 B
    float*  pp1    = (float*)(ws + 25608192);           // 12,804,096 B
    int*    csr    = (int*)  (ws + 38412288);           // <= 9,600,000 B
    int*    deg    = (int*)  (ws + 48012288);           //    200,000 B
    float*  dinv   = (float*)(ws + 48212288);           //    200,000 B
    float*  rd     = (float*)(ws + 48412288);           //    200,000 B
    int*    rptr   = (int*)  (ws + 48612288);           //    200,004 B
    int*    cursor = (int*)  (ws + 48812292);           //    200,000 B
    int*    part   = (int*)  (ws + 49012292);           //        784 B
    int*    coff   = (int*)  (ws + 49013076);           //        784 B

    // 1) convert X/W1 to bf16, then GEMM1 (uses only Xb/W1b/H)
    xb_k<<<12564, 256, 0, stream>>>(X, W1, Xb, W1b);
    gemm1_k<<<dim3(391, 2), 256, 0, stream>>>(Xb, W1b, H);

    // 2) Xb region now dead -> CSR build + hop-state setup in its place
    hipMemsetAsync(deg, 0, N_NODES * sizeof(int), stream);
    hipMemsetAsync(cursor, 0, N_NODES * sizeof(int), stream);
    deg_k<<<50000, 256, 0, stream>>>(dst, deg);
    dinv_k<<<196, 256, 0, stream>>>(deg, dinv, rd);
    scan_p1<<<196, 256, 0, stream>>>(deg, part);
    scan_p2<<<1, 256, 0, stream>>>(part, coff, rptr);
    scan_p3<<<196, 256, 0, stream>>>(deg, coff, rptr);
    scatter_k<<<50000, 256, 0, stream>>>(src, dst, rptr, cursor, csr);
    padfill_k<<<196, 256, 0, stream>>>(deg, rptr, csr);

    // 3) GEMM2 (reads H + dinv, writes h0t), then hops
    gemm2_k<<<391, 256, 0, stream>>>(H, W2, dinv, h0t);
    zdum_k<<<1, 256, 0, stream>>>(h0t, pp0, pp1);

    const float* p = h0t;
    float* bufs[2] = {pp0, pp1};
    for (int k = 0; k < K_HOPS; ++k) {
        float* nx = bufs[k & 1];
        hop_k<<<HOP_GRID, 256, 0, stream>>>(p, h0t, nx, csr, rptr, dinv);
        p = nx;
    }
    logsm_k<<<12500, 256, 0, stream>>>(p, rd, (float*)d_out);
}

// Round 9
// 722.973 us; speedup vs baseline: 1.8703x; 1.2414x over previous
//
#include <hip/hip_runtime.h>
#include <hip/hip_bf16.h>
#include <cstdint>
#include <cstddef>

#define N_NODES 50000
#define N_EDGES 1600000
#define N_FEAT  512
#define N_HID   256
#define N_CLS   64
#define K_HOPS  10
#define NPAD    50016                       // plane rows incl. dummy zero row
#define DUMMY   N_NODES                     // pad edges point here (zeroed)
#define P16(d) (((d) + 15) & ~15)
#define STAGE_CAP 256                       // csr entries staged in LDS per wave
#define HOP_GRID 3125                       // 16 nodes/block x 3125 = 50000
#define NPS 6250                            // nodes per XCD slice (CSR build)

typedef __attribute__((ext_vector_type(4))) float f32x4;
typedef __attribute__((ext_vector_type(8))) short s16x8;

__device__ __forceinline__ ushort f2bf(float f) {
    uint32_t u = __float_as_uint(f);
    uint32_t r = (u + 0x7FFFu + ((u >> 16) & 1u)) >> 16;
    return (ushort)r;
}

// packed fp32x2 -> bf16x2, single VALU op. NON-volatile: pure, schedulable.
__device__ __forceinline__ uint32_t cvtpk(float a, float b) {
    uint32_t r;
    asm("v_cvt_pk_bf16_f32 %0, %1, %2" : "=v"(r) : "v"(a), "v"(b));
    return r;
}

// ------- prepass: X (and W1) fp32 -> bf16, pure streaming, full occupancy ------
__global__ void xb_k(const float* __restrict__ X, const float* __restrict__ W1,
                     ushort* __restrict__ Xb, ushort* __restrict__ W1b) {
    const size_t NX = (size_t)N_NODES * N_FEAT;   // 25,600,000
    const size_t NW = (size_t)N_HID * N_FEAT;     // 131,072
    size_t i = ((size_t)blockIdx.x * 256 + threadIdx.x) * 8;
    if (i < NX) {
        const f32x4 a = *reinterpret_cast<const f32x4*>(X + i);
        const f32x4 b = *reinterpret_cast<const f32x4*>(X + i + 4);
        uint4 o;
        o.x = cvtpk(a[0], a[1]); o.y = cvtpk(a[2], a[3]);
        o.z = cvtpk(b[0], b[1]); o.w = cvtpk(b[2], b[3]);
        *reinterpret_cast<uint4*>(Xb + i) = o;
    } else {
        size_t j = i - NX;
        if (j < NW) {
            const f32x4 a = *reinterpret_cast<const f32x4*>(W1 + j);
            const f32x4 b = *reinterpret_cast<const f32x4*>(W1 + j + 4);
            uint4 o;
            o.x = cvtpk(a[0], a[1]); o.y = cvtpk(a[2], a[3]);
            o.z = cvtpk(b[0], b[1]); o.w = cvtpk(b[2], b[3]);
            *reinterpret_cast<uint4*>(W1b + j) = o;
        }
    }
}

// ---- GEMM1: H = relu(Xb @ W1b^T), bf16 inputs, pure-copy staging --------------
__launch_bounds__(256)
__global__ void gemm1_k(const ushort* __restrict__ Xb, const ushort* __restrict__ W1b,
                        ushort* __restrict__ H) {
    __shared__ ushort sA[128 * 64];
    __shared__ ushort sB[128 * 64];
    const int m0 = blockIdx.x * 128;
    const int n0 = blockIdx.y * 128;
    const int t = threadIdx.x;
    const int wid = t >> 6, lane = t & 63;
    const int wr = wid >> 1, wc = wid & 1;
    const int lo = lane & 15, hi = lane >> 4;

    f32x4 acc[4][4] = {};

    for (int kt = 0; kt < N_FEAT; kt += 64) {
        #pragma unroll
        for (int p = 0; p < 4; ++p) {
            int idx = p * 256 + t;
            int row = idx >> 3, g = idx & 7;
            int grow = m0 + row; if (grow > N_NODES - 1) grow = N_NODES - 1;
            uint4 v = *reinterpret_cast<const uint4*>(Xb + (size_t)grow * N_FEAT + kt + g * 8);
            *reinterpret_cast<uint4*>(&sA[row * 64 + ((g ^ (row & 7)) << 3)]) = v;
        }
        #pragma unroll
        for (int p = 0; p < 4; ++p) {
            int idx = p * 256 + t;
            int row = idx >> 3, g = idx & 7;
            uint4 v = *reinterpret_cast<const uint4*>(W1b + (size_t)(n0 + row) * N_FEAT + kt + g * 8);
            *reinterpret_cast<uint4*>(&sB[row * 64 + ((g ^ (row & 7)) << 3)]) = v;
        }
        __syncthreads();
        #pragma unroll
        for (int kk = 0; kk < 2; ++kk) {
            const int g = kk * 4 + hi;
            s16x8 a[4], b[4];
            #pragma unroll
            for (int i = 0; i < 4; ++i) {
                int row = wr * 64 + i * 16 + lo;
                a[i] = *reinterpret_cast<const s16x8*>(&sA[row * 64 + ((g ^ (row & 7)) << 3)]);
            }
            #pragma unroll
            for (int j = 0; j < 4; ++j) {
                int row = wc * 64 + j * 16 + lo;
                b[j] = *reinterpret_cast<const s16x8*>(&sB[row * 64 + ((g ^ (row & 7)) << 3)]);
            }
            #pragma unroll
            for (int i = 0; i < 4; ++i)
                #pragma unroll
                for (int j = 0; j < 4; ++j)
                    acc[i][j] = __builtin_amdgcn_mfma_f32_16x16x32_bf16(a[i], b[j], acc[i][j], 0, 0, 0);
        }
        __syncthreads();
    }
    #pragma unroll
    for (int i = 0; i < 4; ++i) {
        int rbase = m0 + wr * 64 + i * 16 + hi * 4;
        #pragma unroll
        for (int j = 0; j < 4; ++j) {
            int col = n0 + wc * 64 + j * 16 + lo;
            #pragma unroll
            for (int r = 0; r < 4; ++r) {
                int row = rbase + r;
                if (row < N_NODES) {
                    float v = acc[i][j][r];
                    H[(size_t)row * N_HID + col] = f2bf(fmaxf(v, 0.0f));
                }
            }
        }
    }
}

// ---- GEMM2: h~0 = dinv * (H @ W2^T), row-major [NPAD][64] ---------------------
__launch_bounds__(256)
__global__ void gemm2_k(const ushort* __restrict__ H, const float* __restrict__ W2,
                        const float* __restrict__ dinv, float* __restrict__ out) {
    __shared__ ushort sA[128 * 64];
    __shared__ ushort sB[64 * 64];
    const int m0 = blockIdx.x * 128;
    const int t = threadIdx.x;
    const int wid = t >> 6, lane = t & 63;
    const int lo = lane & 15, hi = lane >> 4;

    f32x4 acc[2][4] = {};

    for (int kt = 0; kt < N_HID; kt += 64) {
        #pragma unroll
        for (int p = 0; p < 4; ++p) {
            int idx = p * 256 + t;
            int row = idx >> 3, g = idx & 7;
            int grow = m0 + row; if (grow > N_NODES - 1) grow = N_NODES - 1;
            uint4 v = *reinterpret_cast<const uint4*>(H + (size_t)grow * N_HID + kt + g * 8);
            *reinterpret_cast<uint4*>(&sA[row * 64 + ((g ^ (row & 7)) << 3)]) = v;
        }
        #pragma unroll
        for (int p = 0; p < 4; ++p) {
            int idx = p * 256 + t;
            int row = idx >> 4, f4 = idx & 15;
            const float4 v = *reinterpret_cast<const float4*>(W2 + (size_t)row * N_HID + kt + f4 * 4);
            uint2 h; h.x = cvtpk(v.x, v.y); h.y = cvtpk(v.z, v.w);
            int g = f4 >> 1;
            int off = row * 64 + ((g ^ (row & 7)) << 3) + ((f4 & 1) << 2);
            *reinterpret_cast<uint2*>(&sB[off]) = h;
        }
        __syncthreads();
        #pragma unroll
        for (int kk = 0; kk < 2; ++kk) {
            const int g = kk * 4 + hi;
            s16x8 a[2], b[4];
            #pragma unroll
            for (int i = 0; i < 2; ++i) {
                int row = wid * 32 + i * 16 + lo;
                a[i] = *reinterpret_cast<const s16x8*>(&sA[row * 64 + ((g ^ (row & 7)) << 3)]);
            }
            #pragma unroll
            for (int j = 0; j < 4; ++j) {
                int row = j * 16 + lo;
                b[j] = *reinterpret_cast<const s16x8*>(&sB[row * 64 + ((g ^ (row & 7)) << 3)]);
            }
            #pragma unroll
            for (int i = 0; i < 2; ++i)
                #pragma unroll
                for (int j = 0; j < 4; ++j)
                    acc[i][j] = __builtin_amdgcn_mfma_f32_16x16x32_bf16(a[i], b[j], acc[i][j], 0, 0, 0);
        }
        __syncthreads();
    }
    // row-major store scaled by dinv: out[row][j*16+lo]
    #pragma unroll
    for (int i = 0; i < 2; ++i) {
        int rbase = m0 + wid * 32 + i * 16 + hi * 4;
        #pragma unroll
        for (int r = 0; r < 4; ++r) {
            int row = rbase + r;
            if (row < N_NODES) {
                const float dv = dinv[row];
                #pragma unroll
                for (int j = 0; j < 4; ++j)
                    out[(size_t)row * 64 + j * 16 + lo] = acc[i][j][r] * dv;
            }
        }
    }
}

// ---------------- degree / dinv / rd (XCD-sliced deg) --------------------------
__global__ void deg_k(const int* __restrict__ dst, int* __restrict__ deg) {
    const int slice = blockIdx.x & 7;
    const int e = (blockIdx.x >> 3) * 256 + threadIdx.x;
    const int lo = slice * NPS;
    const int d = dst[e];
    if ((unsigned)(d - lo) < (unsigned)NPS) atomicAdd(&deg[d], 1);
}

__global__ void dinv_k(const int* __restrict__ deg, float* __restrict__ dinv,
                       float* __restrict__ rd) {
    int n = blockIdx.x * 256 + threadIdx.x;
    if (n < N_NODES) {
        float dp1 = (float)deg[n] + 1.0f;     // +1 self loop
        dinv[n] = rsqrtf(dp1);
        rd[n]   = sqrtf(dp1);
    }
}

// ------------- CSR build: scan over PADDED degrees + scatter + padfill ---------
__device__ __forceinline__ int wave_incl_scan(int v, int lane) {
    #pragma unroll
    for (int d = 1; d < 64; d <<= 1) {
        int u = __shfl_up(v, d, 64);
        if (lane >= d) v += u;
    }
    return v;
}

__global__ void scan_p1(const int* __restrict__ cnt, int* __restrict__ partial) {
    int i = blockIdx.x * 256 + threadIdx.x;
    int v = (i < N_NODES) ? P16(cnt[i]) : 0;
    #pragma unroll
    for (int d = 32; d; d >>= 1) v += __shfl_xor(v, d, 64);
    __shared__ int wt[4];
    int wid = threadIdx.x >> 6, lane = threadIdx.x & 63;
    if (lane == 0) wt[wid] = v;
    __syncthreads();
    if (threadIdx.x == 0) partial[blockIdx.x] = wt[0] + wt[1] + wt[2] + wt[3];
}

__global__ void scan_p2(const int* __restrict__ partial, int* __restrict__ chunkoff,
                        int* __restrict__ row_ptr) {
    int t = threadIdx.x;
    int v = (t < 196) ? partial[t] : 0;
    int lane = t & 63, wid = t >> 6;
    int incl = wave_incl_scan(v, lane);
    __shared__ int wt[4];
    if (lane == 63) wt[wid] = incl;
    __syncthreads();
    int woff = 0;
    for (int w = 0; w < wid; ++w) woff += wt[w];
    int excl = incl - v + woff;
    if (t < 196) chunkoff[t] = excl;
    if (t == 0) row_ptr[N_NODES] = wt[0] + wt[1] + wt[2] + wt[3];  // padded total
}

__global__ void scan_p3(const int* __restrict__ cnt, const int* __restrict__ chunkoff,
                        int* __restrict__ row_ptr) {
    int i = blockIdx.x * 256 + threadIdx.x;
    int v = (i < N_NODES) ? P16(cnt[i]) : 0;
    int lane = threadIdx.x & 63, wid = threadIdx.x >> 6;
    int incl = wave_incl_scan(v, lane);
    __shared__ int wt[4];
    if (lane == 63) wt[wid] = incl;
    __syncthreads();
    int woff = 0;
    for (int w = 0; w < wid; ++w) woff += wt[w];
    int excl = incl - v + woff;
    if (i < N_NODES) row_ptr[i] = chunkoff[blockIdx.x] + excl;
}

__global__ void scatter_k(const int* __restrict__ src, const int* __restrict__ dst,
                          const int* __restrict__ row_ptr,
                          int* __restrict__ cursor, int* __restrict__ csr) {
    const int slice = blockIdx.x & 7;
    const int e = (blockIdx.x >> 3) * 256 + threadIdx.x;
    const int lo = slice * NPS;
    const int d = dst[e];
    if ((unsigned)(d - lo) < (unsigned)NPS) {
        int pos = atomicAdd(&cursor[d], 1);
        csr[row_ptr[d] + pos] = src[e];
    }
}

__global__ void padfill_k(const int* __restrict__ deg, const int* __restrict__ row_ptr,
                          int* __restrict__ csr) {
    int n = blockIdx.x * 256 + threadIdx.x;
    if (n >= N_NODES) return;
    int d = deg[n];
    int base = row_ptr[n] + d;
    int pad = P16(d) - d;
    for (int i = 0; i < pad; ++i) csr[base + i] = DUMMY;
}

// zero the dummy row (64 floats) in the 3 state buffers
__global__ void zdum_k(float* __restrict__ b0, float* __restrict__ b1,
                       float* __restrict__ b2) {
    int t = threadIdx.x;
    if (t >= 192) return;
    float* b = (t < 64) ? b0 : (t < 128) ? b1 : b2;
    int w = t & 63;
    b[(size_t)DUMMY * 64 + w] = 0.0f;
}

// ---------------- one APPNP hop: single-pass full-row (r1 structure + all wins)-
// p~'[d] = 0.9*dinv[d]^2*(sum_{s in N(d)} p~[s] + p~[d]) + 0.1*h~0[d]
// Planes row-major [NPAD][64] fp32 (256B rows). Wave = 4 edge-slots x 16 lanes
// x f32x4 (full row per edge). 16-entry iterations: 4 independent gathers in
// flight per lane (MLP), no predication (P16-padded segments, batches never
// straddle nodes; pads hit the zeroed DUMMY row). 4 nodes/wave, combined csr
// segment LDS-staged with 4 parallel nt loads. Single pass: 2M edge-visits/hop
// (vs 8M chunked) — instruction count per edge is the binding constraint (r8).
__launch_bounds__(256)
__global__ void hop_k(const float* __restrict__ prev, const float* __restrict__ h0,
                      float* __restrict__ next, const int* __restrict__ csr,
                      const int* __restrict__ row_ptr, const float* __restrict__ dinv) {
    __shared__ int scsr[4][STAGE_CAP];
    const int bid = blockIdx.x;
    const int wid = threadIdx.x >> 6;
    const int lane = threadIdx.x & 63;
    const int nb = bid * 16 + wid * 4;             // first of this wave's 4 nodes
    const int slot = lane >> 4;                    // edge slot 0..3
    const int cq = (lane & 15) << 2;               // float offset in 64-f row

    // padded segment boundaries -> SGPRs (uniform loop bounds)
    const int b0 = __builtin_amdgcn_readfirstlane(row_ptr[nb]);
    const int e0 = __builtin_amdgcn_readfirstlane(row_ptr[nb + 1]);
    const int e1 = __builtin_amdgcn_readfirstlane(row_ptr[nb + 2]);
    const int e2 = __builtin_amdgcn_readfirstlane(row_ptr[nb + 3]);
    const int e3 = __builtin_amdgcn_readfirstlane(row_ptr[nb + 4]);
    const int tot = e3 - b0;

    // stage combined range into LDS (4 independent nt loads per lane)
    int* sw = scsr[wid];
    #pragma unroll
    for (int k = 0; k < 4; ++k) {
        int off = k * 64 + lane;
        if (off < tot && off < STAGE_CAP)
            sw[off] = __builtin_nontemporal_load(csr + b0 + off);
    }

    f32x4 a0 = {0.f,0.f,0.f,0.f}, a1 = a0, a2 = a0, a3 = a0;

// 16 entries per iteration: this lane's slot handles 4 of them -> 4 gathers
// in flight. Segments are 16-multiples, so a batch never straddles nodes.
#define NODE_LOOP(Bg, Eg, ACC)                                                   \
    for (int ib = (Bg); ib < (Eg); ib += 16) {                                   \
        int s0, s1, s2, s3;                                                      \
        if (ib + 16 - b0 <= STAGE_CAP) {                                         \
            int base = ib - b0 + slot;                                           \
            s0 = sw[base]; s1 = sw[base + 4]; s2 = sw[base + 8]; s3 = sw[base + 12]; \
        } else {                                                                 \
            s0 = __builtin_nontemporal_load(csr + ib + slot);                    \
            s1 = __builtin_nontemporal_load(csr + ib + slot + 4);                \
            s2 = __builtin_nontemporal_load(csr + ib + slot + 8);                \
            s3 = __builtin_nontemporal_load(csr + ib + slot + 12);               \
        }                                                                        \
        const f32x4 p0 = *reinterpret_cast<const f32x4*>(prev + (size_t)s0 * 64 + cq); \
        const f32x4 p1 = *reinterpret_cast<const f32x4*>(prev + (size_t)s1 * 64 + cq); \
        const f32x4 p2 = *reinterpret_cast<const f32x4*>(prev + (size_t)s2 * 64 + cq); \
        const f32x4 p3 = *reinterpret_cast<const f32x4*>(prev + (size_t)s3 * 64 + cq); \
        _Pragma("unroll")                                                        \
        for (int c = 0; c < 4; ++c) {                                            \
            ACC[c] += p0[c]; ACC[c] += p1[c]; ACC[c] += p2[c]; ACC[c] += p3[c];  \
        }                                                                        \
    }

    NODE_LOOP(b0, e0, a0)
    NODE_LOOP(e0, e1, a1)
    NODE_LOOP(e1, e2, a2)
    NODE_LOOP(e2, e3, a3)
#undef NODE_LOOP

    // fold the 4 edge slots (lane bits 4,5)
    #pragma unroll
    for (int c = 0; c < 4; ++c) {
        a0[c] += __shfl_xor(a0[c], 16, 64); a0[c] += __shfl_xor(a0[c], 32, 64);
        a1[c] += __shfl_xor(a1[c], 16, 64); a1[c] += __shfl_xor(a1[c], 32, 64);
        a2[c] += __shfl_xor(a2[c], 16, 64); a2[c] += __shfl_xor(a2[c], 32, 64);
        a3[c] += __shfl_xor(a3[c], 16, 64); a3[c] += __shfl_xor(a3[c], 32, 64);
    }

    // slot s owns node nb+s: 16 lanes x 16B = one coalesced 256B row store
    {
        const int node = nb + slot;
        const float di = dinv[node];
        const float di2 = di * di;
        f32x4 av = a0;
        if (slot == 1) av = a1;
        if (slot == 2) av = a2;
        if (slot == 3) av = a3;
        const size_t off = (size_t)node * 64 + cq;
        const f32x4 pv = *reinterpret_cast<const f32x4*>(prev + off);  // self loop
        const f32x4 hh = __builtin_nontemporal_load(
            reinterpret_cast<const f32x4*>(h0 + off));
        f32x4 r;
        #pragma unroll
        for (int c = 0; c < 4; ++c)
            r[c] = 0.9f * di2 * (av[c] + pv[c]) + 0.1f * hh[c];
        __builtin_nontemporal_store(r, reinterpret_cast<f32x4*>(next + off));
    }
}

// ---- log_softmax over 64 classes; input scaled planes, rescale by rd ----------
__launch_bounds__(256)
__global__ void logsm_k(const float* __restrict__ in, const float* __restrict__ rd,
                        float* __restrict__ out) {
    int r = (blockIdx.x * 256 + threadIdx.x) >> 6;
    int lane = threadIdx.x & 63;
    if (r >= N_NODES) return;
    float v = in[(size_t)r * 64 + lane] * rd[r];
    float m = v;
    #pragma unroll
    for (int d = 32; d; d >>= 1) m = fmaxf(m, __shfl_xor(m, d, 64));
    float e = __expf(v - m);
    float s = e;
    #pragma unroll
    for (int d = 32; d; d >>= 1) s += __shfl_xor(s, d, 64);
    out[(size_t)r * N_CLS + lane] = (v - m) - __logf(s);
}

extern "C" void kernel_launch(void* const* d_in, const int* in_sizes, int n_in,
                              void* d_out, int out_size, void* d_ws, size_t ws_size,
                              hipStream_t stream) {
    const float* X  = (const float*)d_in[0];
    const int*   EI = (const int*)d_in[1];
    const float* W1 = (const float*)d_in[2];
    const float* W2 = (const float*)d_in[3];
    const int* src = EI;
    const int* dst = EI + N_EDGES;

    char* ws = (char*)d_ws;
    // Lifetimes: Xb/W1b live [xb_k, gemm1]; hop-state reuses those bytes after.
    ushort* Xb     = (ushort*)(ws + 0);                 // 51,200,000 B
    ushort* W1b    = (ushort*)(ws + 51200000);          //    262,144 B
    ushort* H      = (ushort*)(ws + 51462144);          // 25,600,000 B
    // reuse of [0, 51.2MB) after gemm1:
    float*  h0t    = (float*)(ws + 0);                  // 12,804,096 B [NPAD][64]
    float*  pp0    = (float*)(ws + 12804096);           // 12,804,096 B
    float*  pp1    = (float*)(ws + 25608192);           // 12,804,096 B
    int*    csr    = (int*)  (ws + 38412288);           // <= 9,600,000 B
    int*    deg    = (int*)  (ws + 48012288);           //    200,000 B
    float*  dinv   = (float*)(ws + 48212288);           //    200,000 B
    float*  rd     = (float*)(ws + 48412288);           //    200,000 B
    int*    rptr   = (int*)  (ws + 48612288);           //    200,004 B
    int*    cursor = (int*)  (ws + 48812292);           //    200,000 B
    int*    part   = (int*)  (ws + 49012292);           //        784 B
    int*    coff   = (int*)  (ws + 49013076);           //        784 B

    // 1) convert X/W1 to bf16, then GEMM1 (uses only Xb/W1b/H)
    xb_k<<<12564, 256, 0, stream>>>(X, W1, Xb, W1b);
    gemm1_k<<<dim3(391, 2), 256, 0, stream>>>(Xb, W1b, H);

    // 2) Xb region now dead -> CSR build + hop-state setup in its place
    hipMemsetAsync(deg, 0, N_NODES * sizeof(int), stream);
    hipMemsetAsync(cursor, 0, N_NODES * sizeof(int), stream);
    deg_k<<<50000, 256, 0, stream>>>(dst, deg);
    dinv_k<<<196, 256, 0, stream>>>(deg, dinv, rd);
    scan_p1<<<196, 256, 0, stream>>>(deg, part);
    scan_p2<<<1, 256, 0, stream>>>(part, coff, rptr);
    scan_p3<<<196, 256, 0, stream>>>(deg, coff, rptr);
    scatter_k<<<50000, 256, 0, stream>>>(src, dst, rptr, cursor, csr);
    padfill_k<<<196, 256, 0, stream>>>(deg, rptr, csr);

    // 3) GEMM2 (reads H + dinv, writes h0t), then hops
    gemm2_k<<<391, 256, 0, stream>>>(H, W2, dinv, h0t);
    zdum_k<<<1, 256, 0, stream>>>(h0t, pp0, pp1);

    const float* p = h0t;
    float* bufs[2] = {pp0, pp1};
    for (int k = 0; k < K_HOPS; ++k) {
        float* nx = bufs[k & 1];
        hop_k<<<HOP_GRID, 256, 0, stream>>>(p, h0t, nx, csr, rptr, dinv);
        p = nx;
    }
    logsm_k<<<12500, 256, 0, stream>>>(p, rd, (float*)d_out);
}